// Round 6
// baseline (495.032 us; speedup 1.0000x reference)
//
#include <hip/hip_runtime.h>

#define NCOL 64
#define NXCD 8

// ---------------- bf16 helpers (RNE pack, bit-shift unpack) ----------------

__device__ __forceinline__ unsigned int bf16pair(float a, float b) {
  unsigned int ua = __float_as_uint(a), ub = __float_as_uint(b);
  ua = (ua + 0x7FFFu + ((ua >> 16) & 1u)) >> 16;
  ub = (ub + 0x7FFFu + ((ub >> 16) & 1u)) >> 16;
  return (ub << 16) | ua;
}
__device__ __forceinline__ float bf_lo(unsigned int v) { return __uint_as_float(v << 16); }
__device__ __forceinline__ float bf_hi(unsigned int v) { return __uint_as_float(v & 0xFFFF0000u); }

// ---------------- degree (XCD-partitioned by dst range) ----------------

__global__ void deg_part(const int* __restrict__ dst, int* __restrict__ degi,
                         int ne, int n) {
  int chunk = (n + NXCD - 1) / NXCD;
  int g = blockIdx.x & (NXCD - 1);
  int lo = g * chunk, hi = min(lo + chunk, n);
  int tid = (blockIdx.x >> 3) * blockDim.x + threadIdx.x;
  int stride = (gridDim.x >> 3) * blockDim.x;
  for (int i = tid; i < ne; i += stride) {
    int d = dst[i];
    if (d >= lo && d < hi) atomicAdd(&degi[d], 1);
  }
}

__global__ void dinv_kernel(const int* __restrict__ degi, float* __restrict__ dinv, int n) {
  int i = blockIdx.x * blockDim.x + threadIdx.x;
  if (i < n) dinv[i] = rsqrtf((float)degi[i] + 1.0f);
}

// ---------------- graph-run boundaries (batch is SORTED -> no atomics) ----------------

__global__ void bounds_kernel(const int* __restrict__ batch, int* __restrict__ startg,
                              int* __restrict__ endg, int n) {
  int i = blockIdx.x * blockDim.x + threadIdx.x;
  if (i >= n) return;
  int b = batch[i];
  if (i == 0) {
    startg[b] = 0;
  } else {
    int bp = batch[i - 1];
    if (b != bp) { startg[b] = i; endg[bp] = i; }
  }
  if (i == n - 1) endg[b] = n;
}

// ---------------- 3-pass exclusive scan of degrees -> rowptr[0..n] + cursor ----------------

#define SCAN_C 8

__global__ void scan_part(const int* __restrict__ degi, int* __restrict__ tsum,
                          int n, int nthreads) {
  int t = blockIdx.x * blockDim.x + threadIdx.x;
  if (t >= nthreads) return;
  int lo = t * SCAN_C, hi = min(lo + SCAN_C, n);
  int s = 0;
  for (int i = lo; i < hi; ++i) s += degi[i];
  tsum[t] = s;
}

__global__ void scan_mid(int* __restrict__ tsum, int* __restrict__ toff, int nthreads) {
  __shared__ int part[1024];
  int t = threadIdx.x;
  int chunk = (nthreads + 1023) >> 10;
  int lo = t * chunk, hi = min(lo + chunk, nthreads);
  int s = 0;
  for (int i = lo; i < hi; ++i) s += tsum[i];
  part[t] = s;
  __syncthreads();
  for (int d = 1; d < 1024; d <<= 1) {
    int v = (t >= d) ? part[t - d] : 0;
    __syncthreads();
    part[t] += v;
    __syncthreads();
  }
  int off = part[t] - s;
  for (int i = lo; i < hi; ++i) { toff[i] = off; off += tsum[i]; }
}

__global__ void scan_fill(const int* __restrict__ degi, const int* __restrict__ toff,
                          int* __restrict__ rowptr, int* __restrict__ cursor,
                          int n, int nthreads) {
  int t = blockIdx.x * blockDim.x + threadIdx.x;
  if (t >= nthreads) return;
  int lo = t * SCAN_C, hi = min(lo + SCAN_C, n);
  int off = toff[t];
  for (int i = lo; i < hi; ++i) {
    rowptr[i] = off;
    cursor[i] = off;
    off += degi[i];
  }
  if (hi == n) rowptr[n] = off;
}

// ---------------- CSR fill (XCD-partitioned) ----------------

__global__ void csr_fill_part(const int* __restrict__ src, const int* __restrict__ dst,
                              int* __restrict__ cursor, int* __restrict__ csr_src,
                              int ne, int n) {
  int chunk = (n + NXCD - 1) / NXCD;
  int g = blockIdx.x & (NXCD - 1);
  int lo = g * chunk, hi = min(lo + chunk, n);
  int tid = (blockIdx.x >> 3) * blockDim.x + threadIdx.x;
  int stride = (gridDim.x >> 3) * blockDim.x;
  for (int i = tid; i < ne; i += stride) {
    int d = dst[i];
    if (d >= lo && d < hi) {
      int pos = atomicAdd(&cursor[d], 1);
      csr_src[pos] = src[i];
    }
  }
}

// ---------------- tall-skinny GEMM, fused row-scale, bf16-packed output ----------------
// Ybf[i, c/2] = pack_bf16( (X[i,:]@W)[c]*dinv[i], (X[i,:]@W)[c+1]*dinv[i] )

template<int K>
__global__ void gemm_scaled(const float* __restrict__ X, const float* __restrict__ W,
                            const float* __restrict__ dinv, unsigned int* __restrict__ Ybf,
                            int n) {
  int i = blockIdx.x * blockDim.x + threadIdx.x;
  if (i >= n) return;
  const float* xr = X + (size_t)i * K;
  float acc[NCOL];
#pragma unroll
  for (int c = 0; c < NCOL; ++c) acc[c] = 0.f;
#pragma unroll 2
  for (int k = 0; k < K; k += 4) {
    float4 xv = *reinterpret_cast<const float4*>(xr + k);
#pragma unroll
    for (int kk = 0; kk < 4; ++kk) {
      float xk = (kk == 0) ? xv.x : (kk == 1) ? xv.y : (kk == 2) ? xv.z : xv.w;
      const float* wr = W + (size_t)(k + kk) * NCOL;
#pragma unroll
      for (int c = 0; c < NCOL; c += 4) {
        float4 wv = *reinterpret_cast<const float4*>(wr + c);
        acc[c + 0] = fmaf(xk, wv.x, acc[c + 0]);
        acc[c + 1] = fmaf(xk, wv.y, acc[c + 1]);
        acc[c + 2] = fmaf(xk, wv.z, acc[c + 2]);
        acc[c + 3] = fmaf(xk, wv.w, acc[c + 3]);
      }
    }
  }
  float d = dinv[i];
  unsigned int* yr = Ybf + (size_t)i * (NCOL / 2);
#pragma unroll
  for (int c = 0; c < NCOL; c += 8) {
    uint4 o;
    o.x = bf16pair(acc[c + 0] * d, acc[c + 1] * d);
    o.y = bf16pair(acc[c + 2] * d, acc[c + 3] * d);
    o.z = bf16pair(acc[c + 4] * d, acc[c + 5] * d);
    o.w = bf16pair(acc[c + 6] * d, acc[c + 7] * d);
    *reinterpret_cast<uint4*>(yr + c / 2) = o;
  }
}

// ---------------- CSR gather-aggregate over bf16 messages ----------------
// wave per dst node; half-wave (32 lanes x uint = 128B) gathers one row,
// the two halves process alternating edges; combine via shfl_xor(32).

template<bool RELU>
__global__ void aggregate(const int* __restrict__ rowptr, const int* __restrict__ csr_src,
                          const unsigned int* __restrict__ Ybf, const float* __restrict__ dinv,
                          const float* __restrict__ bias, float* __restrict__ H, int n) {
  int nd = (blockIdx.x * blockDim.x + threadIdx.x) >> 6;
  if (nd >= n) return;
  nd = __builtin_amdgcn_readfirstlane(nd);   // wave-uniform -> scalar rowptr loads
  int lane = threadIdx.x & 63;
  int c2 = lane & 31;          // uint index within the 32-uint row
  int half = lane >> 5;        // 0: even edges (+self), 1: odd edges
  int lo = rowptr[nd], hi = rowptr[nd + 1];
  float ax = 0.f, ay = 0.f;
  if (half == 0) {             // self-loop term
    unsigned int v = Ybf[(size_t)nd * 32 + c2];
    ax = bf_lo(v); ay = bf_hi(v);
  }
  int p = lo + half;
  for (; p + 6 < hi; p += 8) { // 4 edges per half per iter (8 per wave)
    int s0 = csr_src[p],     s1 = csr_src[p + 2];
    int s2 = csr_src[p + 4], s3 = csr_src[p + 6];
    unsigned int v0 = Ybf[(size_t)s0 * 32 + c2];
    unsigned int v1 = Ybf[(size_t)s1 * 32 + c2];
    unsigned int v2 = Ybf[(size_t)s2 * 32 + c2];
    unsigned int v3 = Ybf[(size_t)s3 * 32 + c2];
    ax += bf_lo(v0); ay += bf_hi(v0);
    ax += bf_lo(v1); ay += bf_hi(v1);
    ax += bf_lo(v2); ay += bf_hi(v2);
    ax += bf_lo(v3); ay += bf_hi(v3);
  }
  for (; p < hi; p += 2) {
    unsigned int v = Ybf[(size_t)csr_src[p] * 32 + c2];
    ax += bf_lo(v); ay += bf_hi(v);
  }
  ax += __shfl_xor(ax, 32);
  ay += __shfl_xor(ay, 32);
  if (half == 0) {
    float d = dinv[nd];
    float vx = fmaf(d, ax, bias[2 * c2]);
    float vy = fmaf(d, ay, bias[2 * c2 + 1]);
    if (RELU) { vx = fmaxf(vx, 0.f); vy = fmaxf(vy, 0.f); }
    reinterpret_cast<float2*>(H)[(size_t)nd * 32 + c2] = make_float2(vx, vy);
  }
}

// ---------------- pooling: pool[g,:] += H over sorted batch runs ----------------

#define NPG 64

__global__ void pool_kernel(const float* __restrict__ H, const int* __restrict__ batch,
                            float* __restrict__ pool, int n) {
  int gid = (blockIdx.x * blockDim.x + threadIdx.x) >> 6;
  int c = threadIdx.x & 63;
  int n0 = gid * NPG;
  if (n0 >= n) return;
  int n1 = min(n0 + NPG, n);
  float acc = 0.f;
  int curg = batch[n0];
  for (int nd = n0; nd < n1; ++nd) {
    int g = batch[nd];
    if (g != curg) {
      atomicAdd(&pool[(size_t)curg * NCOL + c], acc);
      acc = 0.f;
      curg = g;
    }
    acc += H[(size_t)nd * NCOL + c];
  }
  atomicAdd(&pool[(size_t)curg * NCOL + c], acc);
}

// ---------------- final tiny GEMM: out = (pool/cnt) @ Wl + bl ----------------

__global__ void final_kernel(const float* __restrict__ pool, const int* __restrict__ startg,
                             const int* __restrict__ endg, const float* __restrict__ Wl,
                             const float* __restrict__ bl, float* __restrict__ out, int ng) {
  int t = threadIdx.x;
  if (t >= ng * 6) return;
  int g = t / 6, o = t % 6;
  float cntf = (float)(endg[g] - startg[g]);
  float inv = 1.0f / fmaxf(cntf, 1.0f);
  float s = 0.f;
#pragma unroll
  for (int c = 0; c < NCOL; ++c) s += pool[(size_t)g * NCOL + c] * Wl[c * 6 + o];
  out[t] = fmaf(s, inv, bl[o]);
}

// ---------------- launch ----------------

extern "C" void kernel_launch(void* const* d_in, const int* in_sizes, int n_in,
                              void* d_out, int out_size, void* d_ws, size_t ws_size,
                              hipStream_t stream) {
  const float* x    = (const float*)d_in[0];
  const int*   ei   = (const int*)d_in[1];
  const int*   batch= (const int*)d_in[2];
  const float* W1   = (const float*)d_in[3];
  const float* b1   = (const float*)d_in[4];
  const float* W2   = (const float*)d_in[5];
  const float* b2   = (const float*)d_in[6];
  const float* Wl   = (const float*)d_in[7];
  const float* bl   = (const float*)d_in[8];
  float* out = (float*)d_out;

  int n  = in_sizes[0] / 128;   // 100000
  int ne = in_sizes[1] / 2;     // 1600000
  int ng = out_size / 6;        // 64
  const int* srcI = ei;
  const int* dstI = ei + ne;

  char* w = (char*)d_ws;
  size_t o = 0;
  auto take = [&](size_t bytes) -> char* {
    char* p = w + o;
    o = (o + bytes + 255) & ~(size_t)255;
    return p;
  };
  float*        dinv    = (float*)take((size_t)n * 4);
  int*          degi    = (int*)  take((size_t)n * 4);
  int*          cursor  = (int*)  take((size_t)n * 4);
  int*          rowptr  = (int*)  take((size_t)(n + 1) * 4);
  int*          csr_src = (int*)  take((size_t)ne * 4);
  unsigned int* Ybf     = (unsigned int*)take((size_t)n * (NCOL / 2) * 4);
  float*        H       = (float*)take((size_t)n * NCOL * 4);
  float*        pool    = (float*)take(4096 * 4);
  int*          startg  = (int*)  take(64 * 4);
  int*          endg    = (int*)  take(64 * 4);
  int*          tsum    = (int*)  take(16384 * 4);
  int*          toff    = (int*)  take(16384 * 4);

  hipMemsetAsync(degi, 0, (size_t)n * 4, stream);
  hipMemsetAsync(pool, 0, 4096 * 4, stream);
  hipMemsetAsync(startg, 0, 64 * 4, stream);
  hipMemsetAsync(endg, 0, 64 * 4, stream);

  int nb256 = (n + 255) / 256;
  int nthreads = (n + SCAN_C - 1) / SCAN_C;
  int nbScan = (nthreads + 255) / 256;

  // CSR build (shared by both layers); XCD-partitioned atomics/writes
  deg_part<<<1024, 256, 0, stream>>>(dstI, degi, ne, n);
  bounds_kernel<<<nb256, 256, 0, stream>>>(batch, startg, endg, n);
  dinv_kernel<<<nb256, 256, 0, stream>>>(degi, dinv, n);
  scan_part<<<nbScan, 256, 0, stream>>>(degi, tsum, n, nthreads);
  scan_mid<<<1, 1024, 0, stream>>>(tsum, toff, nthreads);
  scan_fill<<<nbScan, 256, 0, stream>>>(degi, toff, rowptr, cursor, n, nthreads);
  csr_fill_part<<<1024, 256, 0, stream>>>(srcI, dstI, cursor, csr_src, ne, n);

  int nbAgg = (n * 64 + 255) / 256;

  // layer 1: Ybf = bf16((x@W1)*dinv) ; H = relu(dinv*(Y_self + sum Y[src]) + b1)
  gemm_scaled<128><<<nb256, 256, 0, stream>>>(x, W1, dinv, Ybf, n);
  aggregate<true><<<nbAgg, 256, 0, stream>>>(rowptr, csr_src, Ybf, dinv, b1, H, n);

  // layer 2: Ybf = bf16((H@W2)*dinv) ; H = dinv*(Y_self + sum Y[src]) + b2
  gemm_scaled<64><<<nb256, 256, 0, stream>>>(H, W2, dinv, Ybf, n);
  aggregate<false><<<nbAgg, 256, 0, stream>>>(rowptr, csr_src, Ybf, dinv, b2, H, n);

  // pool + head
  int ngroups = (n + NPG - 1) / NPG;
  int pblocks = (ngroups * 64 + 255) / 256;
  pool_kernel<<<pblocks, 256, 0, stream>>>(H, batch, pool, n);
  final_kernel<<<1, 384, 0, stream>>>(pool, startg, endg, Wl, bl, out, ng);
}

// Round 7
// 368.334 us; speedup vs baseline: 1.3440x; 1.3440x over previous
//
#include <hip/hip_runtime.h>

#define NCOL 64
#define NXCD 8

// ---------------- bf16 helpers (RNE pack, bit-shift unpack) ----------------

__device__ __forceinline__ unsigned int bf16pair(float a, float b) {
  unsigned int ua = __float_as_uint(a), ub = __float_as_uint(b);
  ua = (ua + 0x7FFFu + ((ua >> 16) & 1u)) >> 16;
  ub = (ub + 0x7FFFu + ((ub >> 16) & 1u)) >> 16;
  return (ub << 16) | ua;
}
__device__ __forceinline__ float bf_lo(unsigned int v) { return __uint_as_float(v << 16); }
__device__ __forceinline__ float bf_hi(unsigned int v) { return __uint_as_float(v & 0xFFFF0000u); }

// ---------------- degree (XCD-partitioned by dst range) ----------------

__global__ void deg_part(const int* __restrict__ dst, int* __restrict__ degi,
                         int ne, int n) {
  int chunk = (n + NXCD - 1) / NXCD;
  int g = blockIdx.x & (NXCD - 1);
  int lo = g * chunk, hi = min(lo + chunk, n);
  int tid = (blockIdx.x >> 3) * blockDim.x + threadIdx.x;
  int stride = (gridDim.x >> 3) * blockDim.x;
  for (int i = tid; i < ne; i += stride) {
    int d = dst[i];
    if (d >= lo && d < hi) atomicAdd(&degi[d], 1);
  }
}

__global__ void dinv_kernel(const int* __restrict__ degi, float* __restrict__ dinv, int n) {
  int i = blockIdx.x * blockDim.x + threadIdx.x;
  if (i < n) dinv[i] = rsqrtf((float)degi[i] + 1.0f);
}

// ---------------- graph-run boundaries (batch is SORTED -> no atomics) ----------------

__global__ void bounds_kernel(const int* __restrict__ batch, int* __restrict__ startg,
                              int* __restrict__ endg, int n) {
  int i = blockIdx.x * blockDim.x + threadIdx.x;
  if (i >= n) return;
  int b = batch[i];
  if (i == 0) {
    startg[b] = 0;
  } else {
    int bp = batch[i - 1];
    if (b != bp) { startg[b] = i; endg[bp] = i; }
  }
  if (i == n - 1) endg[b] = n;
}

// ---------------- 3-pass exclusive scan of degrees -> rowptr[0..n] + cursor ----------------

#define SCAN_C 8

__global__ void scan_part(const int* __restrict__ degi, int* __restrict__ tsum,
                          int n, int nthreads) {
  int t = blockIdx.x * blockDim.x + threadIdx.x;
  if (t >= nthreads) return;
  int lo = t * SCAN_C, hi = min(lo + SCAN_C, n);
  int s = 0;
  for (int i = lo; i < hi; ++i) s += degi[i];
  tsum[t] = s;
}

__global__ void scan_mid(int* __restrict__ tsum, int* __restrict__ toff, int nthreads) {
  __shared__ int part[1024];
  int t = threadIdx.x;
  int chunk = (nthreads + 1023) >> 10;
  int lo = t * chunk, hi = min(lo + chunk, nthreads);
  int s = 0;
  for (int i = lo; i < hi; ++i) s += tsum[i];
  part[t] = s;
  __syncthreads();
  for (int d = 1; d < 1024; d <<= 1) {
    int v = (t >= d) ? part[t - d] : 0;
    __syncthreads();
    part[t] += v;
    __syncthreads();
  }
  int off = part[t] - s;
  for (int i = lo; i < hi; ++i) { toff[i] = off; off += tsum[i]; }
}

__global__ void scan_fill(const int* __restrict__ degi, const int* __restrict__ toff,
                          int* __restrict__ rowptr, int* __restrict__ cursor,
                          int n, int nthreads) {
  int t = blockIdx.x * blockDim.x + threadIdx.x;
  if (t >= nthreads) return;
  int lo = t * SCAN_C, hi = min(lo + SCAN_C, n);
  int off = toff[t];
  for (int i = lo; i < hi; ++i) {
    rowptr[i] = off;
    cursor[i] = off;
    off += degi[i];
  }
  if (hi == n) rowptr[n] = off;
}

// ---------------- CSR fill (XCD-partitioned) ----------------

__global__ void csr_fill_part(const int* __restrict__ src, const int* __restrict__ dst,
                              int* __restrict__ cursor, int* __restrict__ csr_src,
                              int ne, int n) {
  int chunk = (n + NXCD - 1) / NXCD;
  int g = blockIdx.x & (NXCD - 1);
  int lo = g * chunk, hi = min(lo + chunk, n);
  int tid = (blockIdx.x >> 3) * blockDim.x + threadIdx.x;
  int stride = (gridDim.x >> 3) * blockDim.x;
  for (int i = tid; i < ne; i += stride) {
    int d = dst[i];
    if (d >= lo && d < hi) {
      int pos = atomicAdd(&cursor[d], 1);
      csr_src[pos] = src[i];
    }
  }
}

// ---------------- tiled tall-skinny GEMM -> bf16 messages ----------------
// Block = 256 threads = 4 waves, owns 64 rows. X tile staged in LDS
// ([64][K+1]: +1 pad -> lane-row reads are 2-way bank = free). Wave w
// owns 16 cols; W address is wave-uniform (readfirstlane) -> s_load only.
// Inner loop per k: 1 ds_read_b32 + 16 FMA(sgpr operand). acc[16]/thread.

template<int K>
__global__ __launch_bounds__(256, 4) void gemm_tiled(
    const float* __restrict__ X, const float* __restrict__ W,
    const float* __restrict__ dinv, unsigned int* __restrict__ Ybf, int n) {
  __shared__ float XS[64][K + 1];
  int tid = threadIdx.x;
  int rows0 = blockIdx.x * 64;

  // stage 64 rows of X (coalesced float4)
  const int K4 = K / 4;
  for (int f = tid; f < 64 * K4; f += 256) {
    int r = f / K4, k4 = (f % K4) * 4;
    int gr = min(rows0 + r, n - 1);
    float4 v = *reinterpret_cast<const float4*>(X + (size_t)gr * K + k4);
    XS[r][k4 + 0] = v.x; XS[r][k4 + 1] = v.y;
    XS[r][k4 + 2] = v.z; XS[r][k4 + 3] = v.w;
  }
  __syncthreads();

  int lane = tid & 63;
  int cgrp = __builtin_amdgcn_readfirstlane(tid >> 6);  // provably wave-uniform
  int gr = rows0 + lane;

  float acc[16];
#pragma unroll
  for (int c = 0; c < 16; ++c) acc[c] = 0.f;

  const float* wbase = W + cgrp * 16;
#pragma unroll 4
  for (int k = 0; k < K; ++k) {
    float xk = XS[lane][k];
    const float* wr = wbase + (size_t)k * NCOL;   // wave-uniform -> scalar loads
#pragma unroll
    for (int c = 0; c < 16; c += 4) {
      float4 wv = *reinterpret_cast<const float4*>(wr + c);
      acc[c + 0] = fmaf(xk, wv.x, acc[c + 0]);
      acc[c + 1] = fmaf(xk, wv.y, acc[c + 1]);
      acc[c + 2] = fmaf(xk, wv.z, acc[c + 2]);
      acc[c + 3] = fmaf(xk, wv.w, acc[c + 3]);
    }
  }

  if (gr < n) {
    float d = dinv[gr];
    unsigned int* yr = Ybf + (size_t)gr * (NCOL / 2) + cgrp * 8;
    uint4 o0, o1;
    o0.x = bf16pair(acc[0] * d,  acc[1] * d);
    o0.y = bf16pair(acc[2] * d,  acc[3] * d);
    o0.z = bf16pair(acc[4] * d,  acc[5] * d);
    o0.w = bf16pair(acc[6] * d,  acc[7] * d);
    o1.x = bf16pair(acc[8] * d,  acc[9] * d);
    o1.y = bf16pair(acc[10] * d, acc[11] * d);
    o1.z = bf16pair(acc[12] * d, acc[13] * d);
    o1.w = bf16pair(acc[14] * d, acc[15] * d);
    *reinterpret_cast<uint4*>(yr) = o0;
    *reinterpret_cast<uint4*>(yr + 4) = o1;
  }
}

// ---------------- CSR gather-aggregate over bf16 messages ----------------
// wave per dst node; half-wave (32 lanes x uint = 128B) gathers one row,
// the two halves process alternating edges; combine via shfl_xor(32).

template<bool RELU>
__global__ void aggregate(const int* __restrict__ rowptr, const int* __restrict__ csr_src,
                          const unsigned int* __restrict__ Ybf, const float* __restrict__ dinv,
                          const float* __restrict__ bias, float* __restrict__ H, int n) {
  int nd = (blockIdx.x * blockDim.x + threadIdx.x) >> 6;
  if (nd >= n) return;
  nd = __builtin_amdgcn_readfirstlane(nd);   // wave-uniform -> scalar rowptr loads
  int lane = threadIdx.x & 63;
  int c2 = lane & 31;          // uint index within the 32-uint row
  int half = lane >> 5;        // 0: even edges (+self), 1: odd edges
  int lo = rowptr[nd], hi = rowptr[nd + 1];
  float ax = 0.f, ay = 0.f;
  if (half == 0) {             // self-loop term
    unsigned int v = Ybf[(size_t)nd * 32 + c2];
    ax = bf_lo(v); ay = bf_hi(v);
  }
  int p = lo + half;
  for (; p + 6 < hi; p += 8) { // 4 edges per half per iter (8 per wave)
    int s0 = csr_src[p],     s1 = csr_src[p + 2];
    int s2 = csr_src[p + 4], s3 = csr_src[p + 6];
    unsigned int v0 = Ybf[(size_t)s0 * 32 + c2];
    unsigned int v1 = Ybf[(size_t)s1 * 32 + c2];
    unsigned int v2 = Ybf[(size_t)s2 * 32 + c2];
    unsigned int v3 = Ybf[(size_t)s3 * 32 + c2];
    ax += bf_lo(v0); ay += bf_hi(v0);
    ax += bf_lo(v1); ay += bf_hi(v1);
    ax += bf_lo(v2); ay += bf_hi(v2);
    ax += bf_lo(v3); ay += bf_hi(v3);
  }
  for (; p < hi; p += 2) {
    unsigned int v = Ybf[(size_t)csr_src[p] * 32 + c2];
    ax += bf_lo(v); ay += bf_hi(v);
  }
  ax += __shfl_xor(ax, 32);
  ay += __shfl_xor(ay, 32);
  if (half == 0) {
    float d = dinv[nd];
    float vx = fmaf(d, ax, bias[2 * c2]);
    float vy = fmaf(d, ay, bias[2 * c2 + 1]);
    if (RELU) { vx = fmaxf(vx, 0.f); vy = fmaxf(vy, 0.f); }
    reinterpret_cast<float2*>(H)[(size_t)nd * 32 + c2] = make_float2(vx, vy);
  }
}

// ---------------- pooling: pool[g,:] += H over sorted batch runs ----------------

#define NPG 64

__global__ void pool_kernel(const float* __restrict__ H, const int* __restrict__ batch,
                            float* __restrict__ pool, int n) {
  int gid = (blockIdx.x * blockDim.x + threadIdx.x) >> 6;
  int c = threadIdx.x & 63;
  int n0 = gid * NPG;
  if (n0 >= n) return;
  int n1 = min(n0 + NPG, n);
  float acc = 0.f;
  int curg = batch[n0];
  for (int nd = n0; nd < n1; ++nd) {
    int g = batch[nd];
    if (g != curg) {
      atomicAdd(&pool[(size_t)curg * NCOL + c], acc);
      acc = 0.f;
      curg = g;
    }
    acc += H[(size_t)nd * NCOL + c];
  }
  atomicAdd(&pool[(size_t)curg * NCOL + c], acc);
}

// ---------------- final tiny GEMM: out = (pool/cnt) @ Wl + bl ----------------

__global__ void final_kernel(const float* __restrict__ pool, const int* __restrict__ startg,
                             const int* __restrict__ endg, const float* __restrict__ Wl,
                             const float* __restrict__ bl, float* __restrict__ out, int ng) {
  int t = threadIdx.x;
  if (t >= ng * 6) return;
  int g = t / 6, o = t % 6;
  float cntf = (float)(endg[g] - startg[g]);
  float inv = 1.0f / fmaxf(cntf, 1.0f);
  float s = 0.f;
#pragma unroll
  for (int c = 0; c < NCOL; ++c) s += pool[(size_t)g * NCOL + c] * Wl[c * 6 + o];
  out[t] = fmaf(s, inv, bl[o]);
}

// ---------------- launch ----------------

extern "C" void kernel_launch(void* const* d_in, const int* in_sizes, int n_in,
                              void* d_out, int out_size, void* d_ws, size_t ws_size,
                              hipStream_t stream) {
  const float* x    = (const float*)d_in[0];
  const int*   ei   = (const int*)d_in[1];
  const int*   batch= (const int*)d_in[2];
  const float* W1   = (const float*)d_in[3];
  const float* b1   = (const float*)d_in[4];
  const float* W2   = (const float*)d_in[5];
  const float* b2   = (const float*)d_in[6];
  const float* Wl   = (const float*)d_in[7];
  const float* bl   = (const float*)d_in[8];
  float* out = (float*)d_out;

  int n  = in_sizes[0] / 128;   // 100000
  int ne = in_sizes[1] / 2;     // 1600000
  int ng = out_size / 6;        // 64
  const int* srcI = ei;
  const int* dstI = ei + ne;

  char* w = (char*)d_ws;
  size_t o = 0;
  auto take = [&](size_t bytes) -> char* {
    char* p = w + o;
    o = (o + bytes + 255) & ~(size_t)255;
    return p;
  };
  float*        dinv    = (float*)take((size_t)n * 4);
  int*          degi    = (int*)  take((size_t)n * 4);
  int*          cursor  = (int*)  take((size_t)n * 4);
  int*          rowptr  = (int*)  take((size_t)(n + 1) * 4);
  int*          csr_src = (int*)  take((size_t)ne * 4);
  unsigned int* Ybf     = (unsigned int*)take((size_t)n * (NCOL / 2) * 4);
  float*        H       = (float*)take((size_t)n * NCOL * 4);
  float*        pool    = (float*)take(4096 * 4);
  int*          startg  = (int*)  take(64 * 4);
  int*          endg    = (int*)  take(64 * 4);
  int*          tsum    = (int*)  take(16384 * 4);
  int*          toff    = (int*)  take(16384 * 4);

  hipMemsetAsync(degi, 0, (size_t)n * 4, stream);
  hipMemsetAsync(pool, 0, 4096 * 4, stream);
  hipMemsetAsync(startg, 0, 64 * 4, stream);
  hipMemsetAsync(endg, 0, 64 * 4, stream);

  int nb256 = (n + 255) / 256;
  int nthreads = (n + SCAN_C - 1) / SCAN_C;
  int nbScan = (nthreads + 255) / 256;

  // CSR build (shared by both layers); XCD-partitioned atomics/writes
  deg_part<<<1024, 256, 0, stream>>>(dstI, degi, ne, n);
  bounds_kernel<<<nb256, 256, 0, stream>>>(batch, startg, endg, n);
  dinv_kernel<<<nb256, 256, 0, stream>>>(degi, dinv, n);
  scan_part<<<nbScan, 256, 0, stream>>>(degi, tsum, n, nthreads);
  scan_mid<<<1, 1024, 0, stream>>>(tsum, toff, nthreads);
  scan_fill<<<nbScan, 256, 0, stream>>>(degi, toff, rowptr, cursor, n, nthreads);
  csr_fill_part<<<1024, 256, 0, stream>>>(srcI, dstI, cursor, csr_src, ne, n);

  int nbAgg = (n * 64 + 255) / 256;
  int nbGemm = (n + 63) / 64;

  // layer 1: Ybf = bf16((x@W1)*dinv) ; H = relu(dinv*(Y_self + sum Y[src]) + b1)
  gemm_tiled<128><<<nbGemm, 256, 0, stream>>>(x, W1, dinv, Ybf, n);
  aggregate<true><<<nbAgg, 256, 0, stream>>>(rowptr, csr_src, Ybf, dinv, b1, H, n);

  // layer 2: Ybf = bf16((H@W2)*dinv) ; H = dinv*(Y_self + sum Y[src]) + b2
  gemm_tiled<64><<<nbGemm, 256, 0, stream>>>(H, W2, dinv, Ybf, n);
  aggregate<false><<<nbAgg, 256, 0, stream>>>(rowptr, csr_src, Ybf, dinv, b2, H, n);

  // pool + head
  int ngroups = (n + NPG - 1) / NPG;
  int pblocks = (ngroups * 64 + 255) / 256;
  pool_kernel<<<pblocks, 256, 0, stream>>>(H, batch, pool, n);
  final_kernel<<<1, 384, 0, stream>>>(pool, startg, endg, Wl, bl, out, ng);
}